// Round 1
// baseline (1000.597 us; speedup 1.0000x reference)
//
#include <hip/hip_runtime.h>
#include <hip/hip_bf16.h>

#define NROWS 131072
#define DIN   768
#define DD    512
#define KK    256
#define NL    4

#define BM 64
#define BK 16
#define MARGIN_TH 1e-3f

// ---------------- precompute: chain maps (fp64-exact argmin) ----------------
// grid 768 = 3 layers * 256 source entries; block 256 (one thread per target j)
__global__ __launch_bounds__(256) void maps_kernel(const float* __restrict__ cb,
                                                   int* __restrict__ maps) {
    int l = blockIdx.x >> 8;       // 0..2
    int k = blockIdx.x & 255;
    const float* src = cb + (size_t)l * KK * DD + (size_t)k * DD;   // residual = cb_l[k]
    const float* tgt = cb + (size_t)(l + 1) * KK * DD;              // codebook l+1
    int j = threadIdx.x;
    const float* cj = tgt + (size_t)j * DD;
    double dot = 0.0, nrm = 0.0;
    for (int d = 0; d < DD; ++d) { double c = cj[d]; dot += (double)src[d] * c; nrm += c * c; }
    double s = -2.0 * dot + nrm;

    __shared__ double sv[256];
    __shared__ int    si[256];
    sv[j] = s; si[j] = j;
    __syncthreads();
    for (int off = 128; off; off >>= 1) {
        if (j < off) {
            double a = sv[j], b = sv[j + off];
            if (b < a || (b == a && si[j + off] < si[j])) { sv[j] = b; si[j] = si[j + off]; }
        }
        __syncthreads();
    }
    if (j == 0) maps[l * KK + k] = si[0];
}

// ---------------- precompute: folded weight W2 = -2*enc_w@cb0^T, c2, counter ----------------
// grid 768 (one block per enc_w row), block 256 (one thread per codebook k)
__global__ __launch_bounds__(256) void w2_kernel(const float* __restrict__ enc_w,
                                                 const float* __restrict__ enc_b,
                                                 const float* __restrict__ cb,
                                                 float* __restrict__ W2,
                                                 float* __restrict__ c2,
                                                 int* __restrict__ counter) {
    int jrow = blockIdx.x;
    __shared__ float wrow[DD];
    for (int d = threadIdx.x; d < DD; d += 256) wrow[d] = enc_w[(size_t)jrow * DD + d];
    __syncthreads();
    int k = threadIdx.x;
    const float* ck = cb + (size_t)k * DD;   // layer-0 codebook
    double dot = 0.0;
    for (int d = 0; d < DD; ++d) dot += (double)wrow[d] * (double)ck[d];
    W2[(size_t)jrow * KK + k] = (float)(-2.0 * dot);
    if (jrow == 0) {
        double db = 0.0, nn = 0.0;
        for (int d = 0; d < DD; ++d) { double c = ck[d]; db += (double)enc_b[d] * c; nn += c * c; }
        c2[k] = (float)(-2.0 * db + nn);
        if (k == 0) *counter = 0;
    }
}

// ---------------- precompute: Tdec[k] = (cb0[k]+cb1[i2]+cb2[i3]+cb3[i4]) @ dec_w + dec_b ----------------
// grid 256 (one block per k), block 256
__global__ __launch_bounds__(256) void tdec_kernel(const float* __restrict__ cb,
                                                   const float* __restrict__ dec_w,
                                                   const float* __restrict__ dec_b,
                                                   const int* __restrict__ maps,
                                                   float* __restrict__ Tdec) {
    int k  = blockIdx.x;
    int i2 = maps[0 * KK + k];
    int i3 = maps[1 * KK + i2];
    int i4 = maps[2 * KK + i3];
    __shared__ double T[DD];
    for (int d = threadIdx.x; d < DD; d += 256)
        T[d] = (double)cb[(size_t)0 * KK * DD + (size_t)k  * DD + d]
             + (double)cb[(size_t)1 * KK * DD + (size_t)i2 * DD + d]
             + (double)cb[(size_t)2 * KK * DD + (size_t)i3 * DD + d]
             + (double)cb[(size_t)3 * KK * DD + (size_t)i4 * DD + d];
    __syncthreads();
    for (int n = threadIdx.x; n < DD; n += 256) {
        double acc = (double)dec_b[n];
        for (int d = 0; d < DD; ++d) acc += T[d] * (double)dec_w[(size_t)d * DD + n];
        Tdec[(size_t)k * DD + n] = (float)acc;
    }
}

// ---------------- bulk: scores = X@W2 + c2, per-row argmin+margin, gather Tdec ----------------
// grid NROWS/BM = 2048, block 256. Each thread: 8 rows x 8 cols micro-tile, cols tx+32j.
__global__ __launch_bounds__(256) void bulk_kernel(const float* __restrict__ X,
                                                   const float* __restrict__ W2,
                                                   const float* __restrict__ c2,
                                                   const float* __restrict__ Tdec,
                                                   float* __restrict__ out,
                                                   int* __restrict__ counter,
                                                   int* __restrict__ list) {
    __shared__ float Xs[BM][20];        // padded to keep 16B-aligned float4 stores
    __shared__ float Ws[BK][256];
    __shared__ float Bv[BM][33];
    __shared__ float Sv[BM][33];
    __shared__ int   Bi[BM][33];
    __shared__ int   rowIdx[BM];

    int tid = threadIdx.x;
    int tx = tid & 31, ty = tid >> 5;           // 32 x 8
    int row0 = blockIdx.x * BM;

    float acc[8][8];
#pragma unroll
    for (int i = 0; i < 8; ++i)
#pragma unroll
        for (int j = 0; j < 8; ++j) acc[i][j] = 0.0f;

    for (int k0 = 0; k0 < DIN; k0 += BK) {
        // X tile: 64 rows x 16 k (each thread one float4)
        {
            int r   = tid >> 2;
            int kk4 = (tid & 3) * 4;
            float4 v = *(const float4*)(X + (size_t)(row0 + r) * DIN + k0 + kk4);
            *(float4*)&Xs[r][kk4] = v;
        }
        // W tile: 16 rows x 256 (each thread 4 float4s)
#pragma unroll
        for (int i = 0; i < 4; ++i) {
            int idx = tid + i * 256;            // 0..1023
            int rr  = idx >> 6;                 // 0..15
            int c4  = (idx & 63) * 4;
            float4 v = *(const float4*)(W2 + (size_t)(k0 + rr) * KK + c4);
            *(float4*)&Ws[rr][c4] = v;
        }
        __syncthreads();
#pragma unroll
        for (int kk = 0; kk < BK; ++kk) {
            float a[8], b[8];
#pragma unroll
            for (int i = 0; i < 8; ++i) a[i] = Xs[ty * 8 + i][kk];
#pragma unroll
            for (int j = 0; j < 8; ++j) b[j] = Ws[kk][tx + 32 * j];
#pragma unroll
            for (int i = 0; i < 8; ++i)
#pragma unroll
                for (int j = 0; j < 8; ++j) acc[i][j] = fmaf(a[i], b[j], acc[i][j]);
        }
        __syncthreads();
    }

    // local top-2 per row (first-index tie-break), then cross-thread reduce
#pragma unroll
    for (int i = 0; i < 8; ++i) {
        float v1 = 3.4e38f, v2 = 3.4e38f;
        int   c1 = 1 << 20;
#pragma unroll
        for (int j = 0; j < 8; ++j) {
            int col = tx + 32 * j;
            float s = acc[i][j] + c2[col];
            if (s < v1 || (s == v1 && col < c1)) { v2 = v1; v1 = s; c1 = col; }
            else if (s < v2) v2 = s;
        }
        int r = ty * 8 + i;
        Bv[r][tx] = v1; Bi[r][tx] = c1; Sv[r][tx] = v2;
    }
    __syncthreads();

    if (tid < BM) {
        int r = tid;
        float v1 = 3.4e38f, v2 = 3.4e38f;
        int   c1 = 1 << 20;
        for (int t = 0; t < 32; ++t) {
            float bv = Bv[r][t], sv = Sv[r][t];
            int   bi = Bi[r][t];
            if (bv < v1 || (bv == v1 && bi < c1)) { v2 = fminf(v1, sv); v1 = bv; c1 = bi; }
            else                                  { v2 = fminf(v2, bv); }
        }
        rowIdx[r] = c1;
        if (v2 - v1 < MARGIN_TH) {
            int pos = atomicAdd(counter, 1);
            list[pos] = row0 + r;
        }
    }
    __syncthreads();

    // gather+write: 64 rows x 512 f32, coalesced float4
#pragma unroll
    for (int m = 0; m < 32; ++m) {
        int lin = m * 256 + tid;          // 0..8191
        int r   = lin >> 7;               // 0..63
        int c4  = (lin & 127) * 4;
        float4 v = *(const float4*)(Tdec + (size_t)rowIdx[r] * DD + c4);
        *(float4*)(out + (size_t)(row0 + r) * DD + c4) = v;
    }
}

// ---------------- refine: fp64-exact re-decision for near-tie rows ----------------
// fixed grid 1024, block 256; grid-stride over list
__global__ __launch_bounds__(256) void refine_kernel(const float* __restrict__ X,
                                                     const float* __restrict__ enc_w,
                                                     const float* __restrict__ enc_b,
                                                     const float* __restrict__ cb,
                                                     const float* __restrict__ Tdec,
                                                     float* __restrict__ out,
                                                     const int* __restrict__ counter,
                                                     const int* __restrict__ list) {
    int cnt = *counter;
    __shared__ double r0[DD];
    __shared__ double sv[256];
    __shared__ int    si[256];
    for (int it = blockIdx.x; it < cnt; it += gridDim.x) {
        int n = list[it];
        const float* xr = X + (size_t)n * DIN;
        for (int d = threadIdx.x; d < DD; d += 256) {
            double acc = (double)enc_b[d];
            for (int j = 0; j < DIN; ++j)
                acc += (double)xr[j] * (double)enc_w[(size_t)j * DD + d];
            r0[d] = acc;
        }
        __syncthreads();
        int k = threadIdx.x;
        const float* ck = cb + (size_t)k * DD;   // layer-0 codebook
        double dot = 0.0, nrm = 0.0;
        for (int d = 0; d < DD; ++d) { double c = ck[d]; dot += r0[d] * c; nrm += c * c; }
        sv[k] = -2.0 * dot + nrm; si[k] = k;
        __syncthreads();
        for (int off = 128; off; off >>= 1) {
            if (k < off) {
                double a = sv[k], b = sv[k + off];
                if (b < a || (b == a && si[k + off] < si[k])) { sv[k] = b; si[k] = si[k + off]; }
            }
            __syncthreads();
        }
        int best = si[0];
        for (int c = threadIdx.x; c < DD; c += 256)
            out[(size_t)n * DD + c] = Tdec[(size_t)best * DD + c];
        __syncthreads();
    }
}

extern "C" void kernel_launch(void* const* d_in, const int* in_sizes, int n_in,
                              void* d_out, int out_size, void* d_ws, size_t ws_size,
                              hipStream_t stream) {
    const float* X     = (const float*)d_in[0];
    const float* enc_w = (const float*)d_in[1];
    const float* enc_b = (const float*)d_in[2];
    const float* cb    = (const float*)d_in[3];
    const float* dec_w = (const float*)d_in[4];
    const float* dec_b = (const float*)d_in[5];
    float* out = (float*)d_out;

    char* ws = (char*)d_ws;
    float* W2      = (float*)(ws + 0);              // 768*256*4  = 786432
    float* c2      = (float*)(ws + 786432);         // 256*4      = 1024
    float* Tdec    = (float*)(ws + 787456);         // 256*512*4  = 524288
    int*   maps    = (int*)  (ws + 1311744);        // 3*256*4    = 3072
    int*   counter = (int*)  (ws + 1314816);        // 4 (+pad)
    int*   list    = (int*)  (ws + 1314848);        // up to NROWS*4

    hipLaunchKernelGGL(maps_kernel, dim3(768),       dim3(256), 0, stream, cb, maps);
    hipLaunchKernelGGL(w2_kernel,   dim3(768),       dim3(256), 0, stream, enc_w, enc_b, cb, W2, c2, counter);
    hipLaunchKernelGGL(tdec_kernel, dim3(256),       dim3(256), 0, stream, cb, dec_w, dec_b, maps, Tdec);
    hipLaunchKernelGGL(bulk_kernel, dim3(NROWS / BM), dim3(256), 0, stream, X, W2, c2, Tdec, out, counter, list);
    hipLaunchKernelGGL(refine_kernel, dim3(1024),    dim3(256), 0, stream, X, enc_w, enc_b, cb, Tdec, out, counter, list);
}

// Round 2
// 505.809 us; speedup vs baseline: 1.9782x; 1.9782x over previous
//
#include <hip/hip_runtime.h>
#include <hip/hip_bf16.h>

#define NROWS 131072
#define DIN   768
#define DD    512
#define KK    256
#define NL    4

#define BM 128
#define BK 32
#define MARGIN_TH 1e-3f

typedef __attribute__((ext_vector_type(8))) short  short8;
typedef __attribute__((ext_vector_type(8))) unsigned short ushort8;
typedef __attribute__((ext_vector_type(4))) float  f32x4;

__device__ inline unsigned short f2bf_rn(float x) {
    unsigned int u = __float_as_uint(x);
    unsigned int r = (u + 0x7fffu + ((u >> 16) & 1u)) >> 16;   // RNE
    return (unsigned short)r;
}
__device__ inline float bf2f(unsigned short h) {
    return __uint_as_float(((unsigned int)h) << 16);
}

// ---------------- precompute: chain maps (fp64-exact argmin) ----------------
__global__ __launch_bounds__(256) void maps_kernel(const float* __restrict__ cb,
                                                   int* __restrict__ maps) {
    int l = blockIdx.x >> 8;
    int k = blockIdx.x & 255;
    const float* src = cb + (size_t)l * KK * DD + (size_t)k * DD;
    const float* tgt = cb + (size_t)(l + 1) * KK * DD;
    int j = threadIdx.x;
    const float* cj = tgt + (size_t)j * DD;
    double dot = 0.0, nrm = 0.0;
    for (int d = 0; d < DD; ++d) { double c = cj[d]; dot += (double)src[d] * c; nrm += c * c; }
    double s = -2.0 * dot + nrm;

    __shared__ double sv[256];
    __shared__ int    si[256];
    sv[j] = s; si[j] = j;
    __syncthreads();
    for (int off = 128; off; off >>= 1) {
        if (j < off) {
            double a = sv[j], b = sv[j + off];
            if (b < a || (b == a && si[j + off] < si[j])) { sv[j] = b; si[j] = si[j + off]; }
        }
        __syncthreads();
    }
    if (j == 0) maps[l * KK + k] = si[0];
}

// ---------------- precompute: W2T (bf16 hi/lo, transposed [K=256][DIN=768]), c2, counter ----------------
// grid 768 (one block per enc_w row = k-dim), block 256 (one thread per codebook entry n)
__global__ __launch_bounds__(256) void w2_kernel(const float* __restrict__ enc_w,
                                                 const float* __restrict__ enc_b,
                                                 const float* __restrict__ cb,
                                                 unsigned short* __restrict__ W2Th,
                                                 unsigned short* __restrict__ W2Tl,
                                                 float* __restrict__ c2,
                                                 int* __restrict__ counter) {
    int jrow = blockIdx.x;
    __shared__ float wrow[DD];
    for (int d = threadIdx.x; d < DD; d += 256) wrow[d] = enc_w[(size_t)jrow * DD + d];
    __syncthreads();
    int k = threadIdx.x;
    const float* ck = cb + (size_t)k * DD;   // layer-0 codebook
    double dot = 0.0;
    for (int d = 0; d < DD; ++d) dot += (double)wrow[d] * (double)ck[d];
    float w = (float)(-2.0 * dot);
    unsigned short h = f2bf_rn(w);
    unsigned short l = f2bf_rn(w - bf2f(h));
    W2Th[(size_t)k * DIN + jrow] = h;
    W2Tl[(size_t)k * DIN + jrow] = l;
    if (jrow == 0) {
        double db = 0.0, nn = 0.0;
        for (int d = 0; d < DD; ++d) { double c = ck[d]; db += (double)enc_b[d] * c; nn += c * c; }
        c2[k] = (float)(-2.0 * db + nn);
        if (k == 0) *counter = 0;
    }
}

// ---------------- precompute: Tdec ----------------
__global__ __launch_bounds__(256) void tdec_kernel(const float* __restrict__ cb,
                                                   const float* __restrict__ dec_w,
                                                   const float* __restrict__ dec_b,
                                                   const int* __restrict__ maps,
                                                   float* __restrict__ Tdec) {
    int k  = blockIdx.x;
    int i2 = maps[0 * KK + k];
    int i3 = maps[1 * KK + i2];
    int i4 = maps[2 * KK + i3];
    __shared__ double T[DD];
    for (int d = threadIdx.x; d < DD; d += 256)
        T[d] = (double)cb[(size_t)0 * KK * DD + (size_t)k  * DD + d]
             + (double)cb[(size_t)1 * KK * DD + (size_t)i2 * DD + d]
             + (double)cb[(size_t)2 * KK * DD + (size_t)i3 * DD + d]
             + (double)cb[(size_t)3 * KK * DD + (size_t)i4 * DD + d];
    __syncthreads();
    for (int n = threadIdx.x; n < DD; n += 256) {
        double acc = (double)dec_b[n];
        for (int d = 0; d < DD; ++d) acc += T[d] * (double)dec_w[(size_t)d * DD + n];
        Tdec[(size_t)k * DD + n] = (float)acc;
    }
}

// ---------------- bulk: MFMA bf16-split scores, per-row top-2, gather Tdec ----------------
// grid 1024, block 512 (8 waves). Block tile 128 rows x 256 cols.
// Wave w: rgroup = w&3 (32 rows), cgroup = w>>2 (128 cols). Micro-tile rf=2 x cf=8.
__global__ __launch_bounds__(512) void bulk_kernel(const float* __restrict__ X,
                                                   const unsigned short* __restrict__ W2Th,
                                                   const unsigned short* __restrict__ W2Tl,
                                                   const float* __restrict__ c2,
                                                   const float* __restrict__ Tdec,
                                                   float* __restrict__ out,
                                                   int* __restrict__ counter,
                                                   int* __restrict__ list) {
    __shared__ __align__(16) unsigned short Xsh[BM][40];
    __shared__ __align__(16) unsigned short Xsl[BM][40];
    __shared__ __align__(16) unsigned short Wsh[KK][40];
    __shared__ __align__(16) unsigned short Wsl[KK][40];
    __shared__ float Rv1[BM][2];
    __shared__ float Rv2[BM][2];
    __shared__ int   Ri1[BM][2];
    __shared__ int   rowIdx[BM];

    const int t    = threadIdx.x;
    const int lane = t & 63;
    const int wv   = t >> 6;
    const int rg   = wv & 3;      // row group (32 rows)
    const int cg   = wv >> 2;     // col group (128 cols)
    const int lr   = lane & 15;
    const int lg   = lane >> 4;
    const int lg8  = lg * 8;
    const int row0 = blockIdx.x * BM;

    f32x4 acc[2][8];
#pragma unroll
    for (int rf = 0; rf < 2; ++rf)
#pragma unroll
        for (int cf = 0; cf < 8; ++cf) acc[rf][cf] = (f32x4){0.f, 0.f, 0.f, 0.f};

    // staging addresses (loop-invariant)
    const int xrow = t >> 2, xk8 = (t & 3) * 8;
    const int wcol = t >> 1, wk8 = (t & 1) * 16;
    const float* xp_base = X + (size_t)(row0 + xrow) * DIN + xk8;
    const unsigned short* wph_base = W2Th + (size_t)wcol * DIN + wk8;
    const unsigned short* wpl_base = W2Tl + (size_t)wcol * DIN + wk8;

    for (int k0 = 0; k0 < DIN; k0 += BK) {
        // --- stage X tile (fp32 -> bf16 hi/lo split) ---
        {
            const float* xp = xp_base + k0;
            float4 x0 = *(const float4*)xp;
            float4 x1 = *(const float4*)(xp + 4);
            ushort8 hv, lv;
#pragma unroll
            for (int j = 0; j < 4; ++j) {
                float x = x0[j];
                unsigned short h = f2bf_rn(x);
                hv[j] = h; lv[j] = f2bf_rn(x - bf2f(h));
            }
#pragma unroll
            for (int j = 0; j < 4; ++j) {
                float x = x1[j];
                unsigned short h = f2bf_rn(x);
                hv[j + 4] = h; lv[j + 4] = f2bf_rn(x - bf2f(h));
            }
            *(ushort8*)&Xsh[xrow][xk8] = hv;
            *(ushort8*)&Xsl[xrow][xk8] = lv;
        }
        // --- stage W tile (pre-split bf16, straight copy) ---
        {
            const unsigned short* ph = wph_base + k0;
            const unsigned short* pl = wpl_base + k0;
            *(ushort8*)&Wsh[wcol][wk8]     = *(const ushort8*)ph;
            *(ushort8*)&Wsh[wcol][wk8 + 8] = *(const ushort8*)(ph + 8);
            *(ushort8*)&Wsl[wcol][wk8]     = *(const ushort8*)pl;
            *(ushort8*)&Wsl[wcol][wk8 + 8] = *(const ushort8*)(pl + 8);
        }
        __syncthreads();

        // --- fragments + MFMA ---
        short8 ah[2], al[2];
#pragma unroll
        for (int rf = 0; rf < 2; ++rf) {
            int row = rg * 32 + rf * 16 + lr;
            ah[rf] = *(const short8*)&Xsh[row][lg8];
            al[rf] = *(const short8*)&Xsl[row][lg8];
        }
#pragma unroll
        for (int cf = 0; cf < 8; ++cf) {
            int col = cg * 128 + cf * 16 + lr;
            short8 bh = *(const short8*)&Wsh[col][lg8];
            short8 bl = *(const short8*)&Wsl[col][lg8];
#pragma unroll
            for (int rf = 0; rf < 2; ++rf) {
                acc[rf][cf] = __builtin_amdgcn_mfma_f32_16x16x32_bf16(ah[rf], bh, acc[rf][cf], 0, 0, 0);
                acc[rf][cf] = __builtin_amdgcn_mfma_f32_16x16x32_bf16(ah[rf], bl, acc[rf][cf], 0, 0, 0);
                acc[rf][cf] = __builtin_amdgcn_mfma_f32_16x16x32_bf16(al[rf], bh, acc[rf][cf], 0, 0, 0);
            }
        }
        __syncthreads();
    }

    // --- epilogue: top-2 per row. C/D layout: col=lane&15, row=(lane>>4)*4+reg ---
    float c2v[8];
#pragma unroll
    for (int cf = 0; cf < 8; ++cf) c2v[cf] = c2[cg * 128 + cf * 16 + lr];

#pragma unroll
    for (int rf = 0; rf < 2; ++rf) {
#pragma unroll
        for (int reg = 0; reg < 4; ++reg) {
            float v1 = 3.4e38f, v2 = 3.4e38f;
            int   c1 = 1 << 20;
#pragma unroll
            for (int cf = 0; cf < 8; ++cf) {
                float s = acc[rf][cf][reg] + c2v[cf];
                int col = cg * 128 + cf * 16 + lr;
                if (s < v1 || (s == v1 && col < c1)) { v2 = v1; v1 = s; c1 = col; }
                else if (s < v2) v2 = s;
            }
            // reduce across the 16 lanes (same lg) covering this row
#pragma unroll
            for (int off = 1; off < 16; off <<= 1) {
                float ov1 = __shfl_xor(v1, off);
                float ov2 = __shfl_xor(v2, off);
                int   oc1 = __shfl_xor(c1, off);
                if (ov1 < v1 || (ov1 == v1 && oc1 < c1)) { v2 = fminf(v1, ov2); v1 = ov1; c1 = oc1; }
                else v2 = fminf(v2, ov1);
            }
            if (lr == 0) {
                int rl = rg * 32 + rf * 16 + lg * 4 + reg;
                Rv1[rl][cg] = v1; Ri1[rl][cg] = c1; Rv2[rl][cg] = v2;
            }
        }
    }
    __syncthreads();

    if (t < BM) {
        float a1 = Rv1[t][0], a2 = Rv2[t][0]; int ac = Ri1[t][0];
        float b1 = Rv1[t][1], b2 = Rv2[t][1]; int bc = Ri1[t][1];
        float v1, v2; int c1;
        if (b1 < a1 || (b1 == a1 && bc < ac)) { v1 = b1; c1 = bc; v2 = fminf(a1, b2); }
        else                                   { v1 = a1; c1 = ac; v2 = fminf(a2, b1); }
        rowIdx[t] = c1;
        if (v2 - v1 < MARGIN_TH) {
            int pos = atomicAdd(counter, 1);
            list[pos] = row0 + t;
        }
    }
    __syncthreads();

    // --- gather + write: 128 rows x 512 f32, coalesced float4 ---
#pragma unroll
    for (int m = 0; m < 32; ++m) {
        int lin = m * 512 + t;            // 0..16383
        int r   = lin >> 7;               // 0..127
        int c4  = (lin & 127) * 4;
        float4 v = *(const float4*)(Tdec + (size_t)rowIdx[r] * DD + c4);
        *(float4*)(out + (size_t)(row0 + r) * DD + c4) = v;
    }
}

// ---------------- refine: fp64-exact re-decision for near-tie rows ----------------
__global__ __launch_bounds__(256) void refine_kernel(const float* __restrict__ X,
                                                     const float* __restrict__ enc_w,
                                                     const float* __restrict__ enc_b,
                                                     const float* __restrict__ cb,
                                                     const float* __restrict__ Tdec,
                                                     float* __restrict__ out,
                                                     const int* __restrict__ counter,
                                                     const int* __restrict__ list) {
    int cnt = *counter;
    __shared__ double r0[DD];
    __shared__ double sv[256];
    __shared__ int    si[256];
    for (int it = blockIdx.x; it < cnt; it += gridDim.x) {
        int n = list[it];
        const float* xr = X + (size_t)n * DIN;
        for (int d = threadIdx.x; d < DD; d += 256) {
            double acc = (double)enc_b[d];
            for (int j = 0; j < DIN; ++j)
                acc += (double)xr[j] * (double)enc_w[(size_t)j * DD + d];
            r0[d] = acc;
        }
        __syncthreads();
        int k = threadIdx.x;
        const float* ck = cb + (size_t)k * DD;
        double dot = 0.0, nrm = 0.0;
        for (int d = 0; d < DD; ++d) { double c = ck[d]; dot += r0[d] * c; nrm += c * c; }
        sv[k] = -2.0 * dot + nrm; si[k] = k;
        __syncthreads();
        for (int off = 128; off; off >>= 1) {
            if (k < off) {
                double a = sv[k], b = sv[k + off];
                if (b < a || (b == a && si[k + off] < si[k])) { sv[k] = b; si[k] = si[k + off]; }
            }
            __syncthreads();
        }
        int best = si[0];
        for (int c = threadIdx.x; c < DD; c += 256)
            out[(size_t)n * DD + c] = Tdec[(size_t)best * DD + c];
        __syncthreads();
    }
}

extern "C" void kernel_launch(void* const* d_in, const int* in_sizes, int n_in,
                              void* d_out, int out_size, void* d_ws, size_t ws_size,
                              hipStream_t stream) {
    const float* X     = (const float*)d_in[0];
    const float* enc_w = (const float*)d_in[1];
    const float* enc_b = (const float*)d_in[2];
    const float* cb    = (const float*)d_in[3];
    const float* dec_w = (const float*)d_in[4];
    const float* dec_b = (const float*)d_in[5];
    float* out = (float*)d_out;

    char* ws = (char*)d_ws;
    unsigned short* W2Th = (unsigned short*)(ws + 0);        // 256*768*2 = 393216
    unsigned short* W2Tl = (unsigned short*)(ws + 393216);   // 393216
    float* c2      = (float*)(ws + 786432);                  // 1024
    float* Tdec    = (float*)(ws + 787456);                  // 524288
    int*   maps    = (int*)  (ws + 1311744);                 // 3072
    int*   counter = (int*)  (ws + 1314816);                 // 4 (+pad)
    int*   list    = (int*)  (ws + 1314848);                 // near-tie rows

    hipLaunchKernelGGL(maps_kernel, dim3(768),        dim3(256), 0, stream, cb, maps);
    hipLaunchKernelGGL(w2_kernel,   dim3(768),        dim3(256), 0, stream, enc_w, enc_b, cb, W2Th, W2Tl, c2, counter);
    hipLaunchKernelGGL(tdec_kernel, dim3(256),        dim3(256), 0, stream, cb, dec_w, dec_b, maps, Tdec);
    hipLaunchKernelGGL(bulk_kernel, dim3(NROWS / BM), dim3(512), 0, stream, X, W2Th, W2Tl, c2, Tdec, out, counter, list);
    hipLaunchKernelGGL(refine_kernel, dim3(1024),     dim3(256), 0, stream, X, enc_w, enc_b, cb, Tdec, out, counter, list);
}

// Round 3
// 441.562 us; speedup vs baseline: 2.2660x; 1.1455x over previous
//
#include <hip/hip_runtime.h>
#include <hip/hip_bf16.h>

#define NROWS 131072
#define DIN   768
#define DD    512
#define KK    256

#define BM    64
#define BK    32
#define NSTEP 24            // DIN/BK
#define MARGIN_TH 1e-3f

typedef __attribute__((ext_vector_type(8))) short  short8;
typedef __attribute__((ext_vector_type(8))) unsigned short ushort8;
typedef __attribute__((ext_vector_type(4))) float  f32x4;

__device__ __forceinline__ unsigned short f2bf_rn(float x) {
    unsigned int u = __float_as_uint(x);
    unsigned int r = (u + 0x7fffu + ((u >> 16) & 1u)) >> 16;   // RNE
    return (unsigned short)r;
}
__device__ __forceinline__ float bf2f(unsigned short h) {
    return __uint_as_float(((unsigned int)h) << 16);
}

__device__ __forceinline__ void gl_lds16(const unsigned short* g, unsigned short* l) {
    __builtin_amdgcn_global_load_lds(
        (const __attribute__((address_space(1))) unsigned int*)g,
        (__attribute__((address_space(3))) unsigned int*)l, 16, 0, 0);
}

// ---------------- fused precompute: maps (blocks 0..767) + W2pre/c2 (blocks 768..1535) ----
// maps: fp64-exact argmin chain tables. w2: W2 = -2*enc_w@cb0^T split to bf16 hi/lo and
// stored in EXACT bulk-LDS tile order: Wp[(s*1024 + lg*256 + col)*8 + j], din = s*32+lg*8+j.
__global__ __launch_bounds__(256) void pre_kernel(const float* __restrict__ enc_w,
                                                  const float* __restrict__ enc_b,
                                                  const float* __restrict__ cb,
                                                  unsigned short* __restrict__ WpH,
                                                  unsigned short* __restrict__ WpL,
                                                  float* __restrict__ c2,
                                                  int* __restrict__ maps,
                                                  int* __restrict__ counter) {
    if (blockIdx.x < 768) {
        // ---- maps role ----
        int l = blockIdx.x >> 8;
        int k = blockIdx.x & 255;
        const float* src = cb + (size_t)l * KK * DD + (size_t)k * DD;
        const float* tgt = cb + (size_t)(l + 1) * KK * DD;
        int j = threadIdx.x;
        const float* cj = tgt + (size_t)j * DD;
        double d0 = 0, d1 = 0, d2 = 0, d3 = 0, n0 = 0, n1 = 0, n2 = 0, n3 = 0;
        for (int d = 0; d < DD; d += 4) {
            float c0 = cj[d], c1 = cj[d + 1], c2_ = cj[d + 2], c3 = cj[d + 3];
            float a0 = src[d], a1 = src[d + 1], a2 = src[d + 2], a3 = src[d + 3];
            d0 += (double)c0 * a0; n0 += (double)c0 * c0;
            d1 += (double)c1 * a1; n1 += (double)c1 * c1;
            d2 += (double)c2_ * a2; n2 += (double)c2_ * c2_;
            d3 += (double)c3 * a3; n3 += (double)c3 * c3;
        }
        double s = -2.0 * (d0 + d1 + d2 + d3) + (n0 + n1 + n2 + n3);

        __shared__ double sv[256];
        __shared__ int    si[256];
        sv[j] = s; si[j] = j;
        __syncthreads();
        for (int off = 128; off; off >>= 1) {
            if (j < off) {
                double a = sv[j], b = sv[j + off];
                if (b < a || (b == a && si[j + off] < si[j])) { sv[j] = b; si[j] = si[j + off]; }
            }
            __syncthreads();
        }
        if (j == 0) maps[l * KK + k] = si[0];
    } else {
        // ---- w2 role ----
        int jrow = blockIdx.x - 768;      // din index 0..767
        __shared__ float wrow[DD];
        for (int d = threadIdx.x; d < DD; d += 256) wrow[d] = enc_w[(size_t)jrow * DD + d];
        __syncthreads();
        int col = threadIdx.x;
        const float* ck = cb + (size_t)col * DD;   // layer-0 codebook entry
        double d0 = 0, d1 = 0, d2 = 0, d3 = 0;
        for (int d = 0; d < DD; d += 4) {
            d0 += (double)wrow[d]     * (double)ck[d];
            d1 += (double)wrow[d + 1] * (double)ck[d + 1];
            d2 += (double)wrow[d + 2] * (double)ck[d + 2];
            d3 += (double)wrow[d + 3] * (double)ck[d + 3];
        }
        float w = (float)(-2.0 * (d0 + d1 + d2 + d3));
        unsigned short h = f2bf_rn(w);
        unsigned short l = f2bf_rn(w - bf2f(h));
        int s  = jrow >> 5;
        int kin = jrow & 31;
        int lg = kin >> 3;
        int j  = kin & 7;
        size_t pos = ((size_t)s * 1024 + (size_t)lg * 256 + col) * 8 + j;
        WpH[pos] = h;
        WpL[pos] = l;
        if (jrow == 0) {
            double db = 0.0, nn = 0.0;
            for (int d = 0; d < DD; ++d) { double c = ck[d]; db += (double)enc_b[d] * c; nn += c * c; }
            c2[col] = (float)(-2.0 * db + nn);
            if (col == 0) *counter = 0;
        }
    }
}

// ---------------- precompute: Tdec[k] = (cb0[k]+cb1[i2]+cb2[i3]+cb3[i4]) @ dec_w + dec_b --
__global__ __launch_bounds__(512) void tdec_kernel(const float* __restrict__ cb,
                                                   const float* __restrict__ dec_w,
                                                   const float* __restrict__ dec_b,
                                                   const int* __restrict__ maps,
                                                   float* __restrict__ Tdec) {
    int k  = blockIdx.x;
    int i2 = maps[0 * KK + k];
    int i3 = maps[1 * KK + i2];
    int i4 = maps[2 * KK + i3];
    __shared__ double T[DD];
    for (int d = threadIdx.x; d < DD; d += 512)
        T[d] = (double)cb[(size_t)0 * KK * DD + (size_t)k  * DD + d]
             + (double)cb[(size_t)1 * KK * DD + (size_t)i2 * DD + d]
             + (double)cb[(size_t)2 * KK * DD + (size_t)i3 * DD + d]
             + (double)cb[(size_t)3 * KK * DD + (size_t)i4 * DD + d];
    __syncthreads();
    int n = threadIdx.x;
    double p0 = 0, p1 = 0, p2 = 0, p3 = 0;
    for (int d = 0; d < DD; d += 4) {
        p0 += T[d]     * (double)dec_w[(size_t)(d)     * DD + n];
        p1 += T[d + 1] * (double)dec_w[(size_t)(d + 1) * DD + n];
        p2 += T[d + 2] * (double)dec_w[(size_t)(d + 2) * DD + n];
        p3 += T[d + 3] * (double)dec_w[(size_t)(d + 3) * DD + n];
    }
    Tdec[(size_t)k * DD + n] = (float)((double)dec_b[n] + p0 + p1 + p2 + p3);
}

// ---------------- bulk: MFMA bf16-split scores, per-row top-2, gather Tdec ----------------
// grid 2048, block 256 (4 waves). Block tile 64 rows x 256 cols; wave tile 64x64 (cg = wave).
// LDS unit layout (16B units): X: u = lg*64+row (XOR-swizzled u^=(lg<<1)); W: u = lg*256+col.
__global__ __launch_bounds__(256, 3) void bulk_kernel(const float* __restrict__ X,
                                                      const unsigned short* __restrict__ WpH,
                                                      const unsigned short* __restrict__ WpL,
                                                      const float* __restrict__ c2,
                                                      const float* __restrict__ Tdec,
                                                      float* __restrict__ out,
                                                      int* __restrict__ counter,
                                                      int* __restrict__ list) {
    __shared__ __align__(16) unsigned char smem[40960];
    unsigned short* Xh = (unsigned short*)smem;              // 4KB: units 0..255
    unsigned short* Xl = (unsigned short*)(smem + 4096);     // 4KB
    unsigned short* Wh = (unsigned short*)(smem + 8192);     // 16KB: units 0..1023
    unsigned short* Wl = (unsigned short*)(smem + 24576);    // 16KB
    // epilogue aliases (used only after the k-loop's final barrier):
    float* Rv1    = (float*)smem;                            // 64*4
    float* Rv2    = (float*)(smem + 1024);                   // 64*4
    int*   Ri1    = (int*)  (smem + 2048);                   // 64*4
    int*   rowIdx = (int*)  (smem + 3072);                   // 64

    const int t    = threadIdx.x;
    const int lane = t & 63;
    const int wv   = t >> 6;        // col-group 0..3 (64 cols each)
    const int lr   = lane & 15;
    const int lg   = lane >> 4;
    const int row0 = blockIdx.x * BM;

    f32x4 acc[4][4];
#pragma unroll
    for (int rf = 0; rf < 4; ++rf)
#pragma unroll
        for (int cf = 0; cf < 4; ++cf) acc[rf][cf] = (f32x4){0.f, 0.f, 0.f, 0.f};

    // X staging addresses (loop-invariant): thread t loads x[row=t>>2][ (t&3)*8 .. +8 ]
    const int xrow = t >> 2, xsub = t & 3;
    const float* xp_base = X + (size_t)(row0 + xrow) * DIN + xsub * 8;
    const int xu = (xsub * 64 + xrow) ^ (xsub << 1);         // swizzled unit
    unsigned short* xh_dst = Xh + xu * 8;
    unsigned short* xl_dst = Xl + xu * 8;

    for (int s = 0; s < NSTEP; ++s) {
        // --- issue W stage first (HBM/L2 latency overlaps the X convert) ---
        const unsigned short* gH = WpH + (size_t)s * 8192;
        const unsigned short* gL = WpL + (size_t)s * 8192;
#pragma unroll
        for (int i = 0; i < 4; ++i) {
            int ub = wv * 256 + i * 64;
            gl_lds16(gH + (size_t)(ub + lane) * 8, Wh + ub * 8);
            gl_lds16(gL + (size_t)(ub + lane) * 8, Wl + ub * 8);
        }
        // --- X stage: fp32 load -> bf16 hi/lo split -> swizzled ds_write ---
        {
            const float* xp = xp_base + s * BK;
            float4 x0 = *(const float4*)xp;
            float4 x1 = *(const float4*)(xp + 4);
            ushort8 hv, lv;
#pragma unroll
            for (int j = 0; j < 4; ++j) {
                float x = x0[j];
                unsigned short h = f2bf_rn(x);
                hv[j] = h; lv[j] = f2bf_rn(x - bf2f(h));
            }
#pragma unroll
            for (int j = 0; j < 4; ++j) {
                float x = x1[j];
                unsigned short h = f2bf_rn(x);
                hv[j + 4] = h; lv[j + 4] = f2bf_rn(x - bf2f(h));
            }
            *(ushort8*)xh_dst = hv;
            *(ushort8*)xl_dst = lv;
        }
        __syncthreads();

        // --- fragments + MFMA (16x16x32 bf16, 3-term split) ---
        short8 ah[4], al[4];
#pragma unroll
        for (int rf = 0; rf < 4; ++rf) {
            int u = (lg * 64 + rf * 16 + lr) ^ (lg << 1);
            ah[rf] = *(const short8*)(Xh + u * 8);
            al[rf] = *(const short8*)(Xl + u * 8);
        }
#pragma unroll
        for (int cf = 0; cf < 4; ++cf) {
            int u = lg * 256 + wv * 64 + cf * 16 + lr;
            short8 bh = *(const short8*)(Wh + u * 8);
            short8 bl = *(const short8*)(Wl + u * 8);
#pragma unroll
            for (int rf = 0; rf < 4; ++rf) {
                acc[rf][cf] = __builtin_amdgcn_mfma_f32_16x16x32_bf16(al[rf], bh, acc[rf][cf], 0, 0, 0);
                acc[rf][cf] = __builtin_amdgcn_mfma_f32_16x16x32_bf16(ah[rf], bl, acc[rf][cf], 0, 0, 0);
                acc[rf][cf] = __builtin_amdgcn_mfma_f32_16x16x32_bf16(ah[rf], bh, acc[rf][cf], 0, 0, 0);
            }
        }
        __syncthreads();
    }

    // --- epilogue: per-row top-2 (C/D layout: col=lane&15, row=(lane>>4)*4+reg) ---
    float c2v[4];
#pragma unroll
    for (int cf = 0; cf < 4; ++cf) c2v[cf] = c2[wv * 64 + cf * 16 + lr];

#pragma unroll
    for (int rf = 0; rf < 4; ++rf) {
#pragma unroll
        for (int reg = 0; reg < 4; ++reg) {
            float v1 = 3.4e38f, v2 = 3.4e38f;
            int   c1 = 1 << 20;
#pragma unroll
            for (int cf = 0; cf < 4; ++cf) {
                float sc = acc[rf][cf][reg] + c2v[cf];
                int col = wv * 64 + cf * 16 + lr;
                if (sc < v1 || (sc == v1 && col < c1)) { v2 = v1; v1 = sc; c1 = col; }
                else if (sc < v2) v2 = sc;
            }
#pragma unroll
            for (int off = 1; off < 16; off <<= 1) {
                float ov1 = __shfl_xor(v1, off);
                float ov2 = __shfl_xor(v2, off);
                int   oc1 = __shfl_xor(c1, off);
                if (ov1 < v1 || (ov1 == v1 && oc1 < c1)) { v2 = fminf(v1, ov2); v1 = ov1; c1 = oc1; }
                else v2 = fminf(v2, ov1);
            }
            if (lr == 0) {
                int r = rf * 16 + lg * 4 + reg;
                Rv1[r * 4 + wv] = v1; Ri1[r * 4 + wv] = c1; Rv2[r * 4 + wv] = v2;
            }
        }
    }
    __syncthreads();

    if (t < BM) {
        float v1 = Rv1[t * 4], v2 = Rv2[t * 4];
        int   c1 = Ri1[t * 4];
#pragma unroll
        for (int g = 1; g < 4; ++g) {
            float bv = Rv1[t * 4 + g], bs = Rv2[t * 4 + g];
            int   bc = Ri1[t * 4 + g];
            if (bv < v1) { v2 = fminf(v1, bs); v1 = bv; c1 = bc; }
            else         { v2 = fminf(v2, bv); }
        }
        rowIdx[t] = c1;
        if (v2 - v1 < MARGIN_TH) {
            int pos = atomicAdd(counter, 1);
            list[pos] = row0 + t;
        }
    }
    __syncthreads();

    // --- gather + write: 64 rows x 512 f32, coalesced float4 ---
#pragma unroll
    for (int m = 0; m < 32; ++m) {
        int lin = m * 256 + t;            // 0..8191
        int r   = lin >> 7;               // 0..63
        int c4  = (lin & 127) * 4;
        float4 v = *(const float4*)(Tdec + (size_t)rowIdx[r] * DD + c4);
        *(float4*)(out + (size_t)(row0 + r) * DD + c4) = v;
    }
}

// ---------------- refine: fp64-exact re-decision for near-tie rows ----------------
__global__ __launch_bounds__(256) void refine_kernel(const float* __restrict__ X,
                                                     const float* __restrict__ enc_w,
                                                     const float* __restrict__ enc_b,
                                                     const float* __restrict__ cb,
                                                     const float* __restrict__ Tdec,
                                                     float* __restrict__ out,
                                                     const int* __restrict__ counter,
                                                     const int* __restrict__ list) {
    int cnt = *counter;
    __shared__ double r0[DD];
    __shared__ double sv[256];
    __shared__ int    si[256];
    for (int it = blockIdx.x; it < cnt; it += gridDim.x) {
        int n = list[it];
        const float* xr = X + (size_t)n * DIN;
        for (int d = threadIdx.x; d < DD; d += 256) {
            double a0 = 0, a1 = 0, a2 = 0, a3 = 0;
            for (int j = 0; j < DIN; j += 4) {
                a0 += (double)xr[j]     * (double)enc_w[(size_t)(j)     * DD + d];
                a1 += (double)xr[j + 1] * (double)enc_w[(size_t)(j + 1) * DD + d];
                a2 += (double)xr[j + 2] * (double)enc_w[(size_t)(j + 2) * DD + d];
                a3 += (double)xr[j + 3] * (double)enc_w[(size_t)(j + 3) * DD + d];
            }
            r0[d] = (double)enc_b[d] + a0 + a1 + a2 + a3;
        }
        __syncthreads();
        int k = threadIdx.x;
        const float* ck = cb + (size_t)k * DD;
        double d0 = 0, d1 = 0, n0 = 0, n1 = 0;
        for (int d = 0; d < DD; d += 2) {
            double c0 = ck[d], c1 = ck[d + 1];
            d0 += r0[d] * c0;     n0 += c0 * c0;
            d1 += r0[d + 1] * c1; n1 += c1 * c1;
        }
        sv[k] = -2.0 * (d0 + d1) + (n0 + n1); si[k] = k;
        __syncthreads();
        for (int off = 128; off; off >>= 1) {
            if (k < off) {
                double a = sv[k], b = sv[k + off];
                if (b < a || (b == a && si[k + off] < si[k])) { sv[k] = b; si[k] = si[k + off]; }
            }
            __syncthreads();
        }
        int best = si[0];
        for (int c = threadIdx.x; c < DD; c += 256)
            out[(size_t)n * DD + c] = Tdec[(size_t)best * DD + c];
        __syncthreads();
    }
}

extern "C" void kernel_launch(void* const* d_in, const int* in_sizes, int n_in,
                              void* d_out, int out_size, void* d_ws, size_t ws_size,
                              hipStream_t stream) {
    const float* X     = (const float*)d_in[0];
    const float* enc_w = (const float*)d_in[1];
    const float* enc_b = (const float*)d_in[2];
    const float* cb    = (const float*)d_in[3];
    const float* dec_w = (const float*)d_in[4];
    const float* dec_b = (const float*)d_in[5];
    float* out = (float*)d_out;

    char* ws = (char*)d_ws;
    unsigned short* WpH = (unsigned short*)(ws + 0);         // 24*1024*8*2 = 393216
    unsigned short* WpL = (unsigned short*)(ws + 393216);    // 393216
    float* c2      = (float*)(ws + 786432);                  // 1024
    float* Tdec    = (float*)(ws + 787456);                  // 524288
    int*   maps    = (int*)  (ws + 1311744);                 // 3072
    int*   counter = (int*)  (ws + 1314816);                 // 4 (+pad)
    int*   list    = (int*)  (ws + 1314848);                 // near-tie rows

    hipLaunchKernelGGL(pre_kernel,  dim3(1536),        dim3(256), 0, stream,
                       enc_w, enc_b, cb, WpH, WpL, c2, maps, counter);
    hipLaunchKernelGGL(tdec_kernel, dim3(256),         dim3(512), 0, stream,
                       cb, dec_w, dec_b, maps, Tdec);
    hipLaunchKernelGGL(bulk_kernel, dim3(NROWS / BM),  dim3(256), 0, stream,
                       X, WpH, WpL, c2, Tdec, out, counter, list);
    hipLaunchKernelGGL(refine_kernel, dim3(1024),      dim3(256), 0, stream,
                       X, enc_w, enc_b, cb, Tdec, out, counter, list);
}